// Round 4
// baseline (219.279 us; speedup 1.0000x reference)
//
#include <hip/hip_runtime.h>
#include <hip/hip_bf16.h>
#include <math.h>

#define HW 9216      // 96*96
#define C2 64
#define NCHUNK 48    // j-split factor (chunk = 96 = 3 full 32-wide tiles)
#define JTILE 32     // j-tile per lane (32 named accumulators)
#define EPSN 1e-8f

// expand M(0)..M(31) in ascending order (order matters for first-max tie-break)
#define REP32(M) M(0) M(1) M(2) M(3) M(4) M(5) M(6) M(7) M(8) M(9) M(10) M(11) \
                 M(12) M(13) M(14) M(15) M(16) M(17) M(18) M(19) M(20) M(21) M(22) \
                 M(23) M(24) M(25) M(26) M(27) M(28) M(29) M(30) M(31)

// ---------------- kernel 1: compaction + amax zero (single block) ---------
// ilist = positions with mask>=1 (flagged i), jlist = positions with mask<1
__global__ void compact_kernel(const int* __restrict__ mask, int* __restrict__ ilist,
                               int* __restrict__ jlist, int* __restrict__ counts,
                               unsigned long long* __restrict__ amax) {
    __shared__ int sc[1024];
    int t = threadIdx.x;
    // zero the argmax merge buffer (ws is poisoned 0xAA before every launch)
#pragma unroll
    for (int k = 0; k < 18; k++) amax[t * 18 + k] = 0ull;   // 1024*18 = 2*HW
    int base = t * 9;
    int f[9]; int cnt = 0;
#pragma unroll
    for (int k = 0; k < 9; k++) { f[k] = (mask[base + k] >= 1) ? 1 : 0; cnt += f[k]; }
    sc[t] = cnt;
    __syncthreads();
#pragma unroll
    for (int off = 1; off < 1024; off <<= 1) {
        int add = (t >= off) ? sc[t - off] : 0;
        __syncthreads();
        sc[t] += add;
        __syncthreads();
    }
    int incl = sc[t];
    int excl = incl - cnt;
    int posF = excl, posU = base - excl;
#pragma unroll
    for (int k = 0; k < 9; k++) {
        int p = base + k;
        if (f[k]) ilist[posF++] = p; else jlist[posU++] = p;
    }
    if (t == 1023) { counts[0] = incl; counts[1] = HW - incl; }
}

// ---------------- kernel 2: build transposed compacted A and B ------------
// amatT[b][c][ci] = lat[b][c][ilist[ci]]                    (unnormalized)
// bmatT[b][c][jj] = lat[b][c][jlist[jj]] / max(||lat_j||,eps)
// zero-padded to HW columns so argmax tails read benign zeros.
__global__ void buildab_kernel(const float* __restrict__ x, const int* __restrict__ ilist,
                               const int* __restrict__ jlist, const int* __restrict__ counts,
                               float* __restrict__ amatT, float* __restrict__ bmatT) {
    int t = blockIdx.x * blockDim.x + threadIdx.x;   // 0 .. 4*HW-1
    if (t >= 4 * HW) return;
    int kind = t / (2 * HW);                         // 0 = A, 1 = B
    int r = t - kind * 2 * HW;
    int b = r / HW, p = r - b * HW;
    int n = kind ? counts[1] : counts[0];
    float v[C2];
    if (p < n) {
        int src = kind ? jlist[p] : ilist[p];
        const float* xl = x + (size_t)(b * 128 + 64) * HW + src;
        float ss = 0.f;
#pragma unroll
        for (int c = 0; c < C2; c++) { float w = xl[(size_t)c * HW]; v[c] = w; ss = fmaf(w, w, ss); }
        if (kind) {
            float inv = 1.0f / fmaxf(sqrtf(ss), EPSN);
#pragma unroll
            for (int c = 0; c < C2; c++) v[c] *= inv;
        }
    } else {
#pragma unroll
        for (int c = 0; c < C2; c++) v[c] = 0.f;
    }
    float* d = (kind ? bmatT : amatT) + (size_t)b * C2 * HW + p;
#pragma unroll
    for (int c = 0; c < C2; c++) d[(size_t)c * HW] = v[c];
}

// ordered-float mapping: monotone bijection float -> uint32 under unsigned compare
__device__ __forceinline__ unsigned int ordf(float f) {
    unsigned int u = __float_as_uint(f);
    return (u & 0x80000000u) ? ~u : (u | 0x80000000u);
}

// ---------------- kernel 3: main argmax-"GEMM" (named-register tiled) -----
// Lane owns one ci and 32 NAMED accumulator floats (pure SSA -> the compiler
// cannot distribute/remat them like it did with float acc[32]). Per c:
// 1 coalesced a-load (L1-hot after tile 0) + 32 FMAs; b-row address is
// wave-uniform -> s_load on the SMEM pipe. First-max tie-break: ascending jb,
// ascending k (macro order), strict >, packed-u64 atomicMax.
__global__ __launch_bounds__(256, 4) void argmax_kernel(
    const float* __restrict__ amatT, const float* __restrict__ bmatT,
    const int* __restrict__ ilist, const int* __restrict__ counts,
    unsigned long long* __restrict__ amax)
{
    int b = blockIdx.z;
    int s = blockIdx.y;
    int ci = blockIdx.x * 256 + threadIdx.x;
    int ni = counts[0], nj = counts[1];
    if (blockIdx.x * 256 >= ni) return;              // dead block
    int chunk = (((nj + NCHUNK - 1) / NCHUNK) + 15) & ~15;   // mult of 16
    int j0 = s * chunk;
    int j1 = min(j0 + chunk, nj);
    const float* ap = amatT + (size_t)b * C2 * HW + ci;   // padded cols -> tail lanes read 0
    const float* bbase = bmatT + (size_t)b * C2 * HW;
    float best = -INFINITY; int bestjj = -1;
    for (int jb = j0; jb < j1; jb += JTILE) {
#define DECLA(k) float acc##k = 0.f;
        REP32(DECLA)
        const float* bp = bbase + jb;
        for (int c = 0; c < C2; ++c) {
            float av = ap[(size_t)c * HW];
            const float* bc = bp + (size_t)c * HW;
#define FMAK(k) acc##k = fmaf(av, bc[k], acc##k);
            REP32(FMAK)
        }
        int lim = j1 - jb;                            // tail guard (padded cols are zeros)
#define SELK(k) if (k < lim && acc##k > best) { best = acc##k; bestjj = jb + k; }
        REP32(SELK)
    }
    if (ci < ni && bestjj >= 0) {
        unsigned long long key = ((unsigned long long)ordf(best) << 32) |
                                 (unsigned long long)(~(unsigned int)bestjj);
        atomicMax(&amax[(size_t)b * HW + ilist[ci]], key);   // indexed by ORIGINAL position
    }
}

// ---------------- kernel 4: fused epilogue (copy + decode + gather) -------
// out channels [0,128): passthrough copy of x (float4).
// out channels [128,192): shift = former at argmax j (0 where !flag).
__global__ void epilogue_kernel(const float4* __restrict__ x4, const float* __restrict__ x,
                                const int* __restrict__ mask,
                                const unsigned long long* __restrict__ amax,
                                const int* __restrict__ jlist, float4* __restrict__ out4) {
    const int q = HW / 4;                            // 2304
    int t = blockIdx.x * blockDim.x + threadIdx.x;   // 0 .. 2*192*q-1
    if (t >= 2 * 192 * q) return;
    int pos4 = t % q;
    int c = (t / q) % 192;
    int b = t / (192 * q);
    if (c < 128) {
        out4[t] = x4[((size_t)b * 128 + c) * q + pos4];
    } else {
        float4 v = make_float4(0.f, 0.f, 0.f, 0.f);
        float* vp = &v.x;
        int pos = pos4 * 4;
        const float* xf = x + (size_t)(b * 128 + (c - 128)) * HW;
#pragma unroll
        for (int k = 0; k < 4; k++) {
            int p = pos + k;
            if (mask[p] >= 1) {
                unsigned long long key = amax[(size_t)b * HW + p];
                int j = 0;                           // nj==0 -> argmax of all-NEG row = 0
                if (key != 0ull) j = jlist[(int)(~(unsigned int)key)];
                vp[k] = xf[j];
            }
        }
        out4[t] = v;
    }
}

extern "C" void kernel_launch(void* const* d_in, const int* in_sizes, int n_in,
                              void* d_out, int out_size, void* d_ws, size_t ws_size,
                              hipStream_t stream) {
    const float* x = (const float*)d_in[0];
    const int* mask = (const int*)d_in[1];
    float4* out4 = (float4*)d_out;

    // workspace layout (64B-aligned): counts | ilist | jlist | amax | amatT | bmatT
    char* ws = (char*)d_ws;
    int*   counts = (int*)ws;                                   // 2 ints (pad to 64)
    int*   ilist  = (int*)(ws + 64);                            // HW ints = 36864 B
    int*   jlist  = (int*)(ws + 64 + 36864);                    // HW ints
    unsigned long long* amax = (unsigned long long*)(ws + 64 + 2 * 36864);   // 2*HW*8 = 147456 B
    float* amatT  = (float*)(ws + 64 + 2 * 36864 + 147456);                  // 2*64*HW*4 = 4718592 B
    float* bmatT  = (float*)(ws + 64 + 2 * 36864 + 147456 + 4718592);        // 4718592 B

    // 1) compaction + amax zeroing
    compact_kernel<<<1, 1024, 0, stream>>>(mask, ilist, jlist, counts, amax);
    // 2) transposed compacted A and normalized B
    buildab_kernel<<<(4 * HW + 255) / 256, 256, 0, stream>>>(x, ilist, jlist, counts, amatT, bmatT);
    // 3) argmax GEMM: grid (i-blocks, j-chunks, batch)
    {
        dim3 grid((HW + 255) / 256, NCHUNK, 2);
        argmax_kernel<<<grid, 256, 0, stream>>>(amatT, bmatT, ilist, counts, amax);
    }
    // 4) fused copy + decode + gather
    {
        int n = 2 * 192 * (HW / 4);
        epilogue_kernel<<<(n + 255) / 256, 256, 0, stream>>>((const float4*)x, x, mask, amax, jlist, out4);
    }
}